// Round 2
// baseline (9.730 us; speedup 1.0000x reference)
//
#include <hip/hip_runtime.h>

// AttentionLayer (AFM-style) on MI355X.
//
// softmax over a size-1 axis == 1.0  =>  attention MLP is dead code.
//   afm[b,e] = sum_{i<j} x[b,i,e]*x[b,j,e]
//            = 0.5 * ( (sum_f x[b,f,e])^2 - sum_f x[b,f,e]^2 )
//
// R1: one wave per batch row (2048 waves -> 2 waves/SIMD), float4 loads
// (16 B/lane = coalescing sweet spot; each wave-load covers 4 contiguous
// 256 B rows), shfl_xor(16,32) tree to combine the 4 row-phases.

__global__ __launch_bounds__(256) void afm_wave_kernel(const float* __restrict__ x,
                                                       float* __restrict__ out,
                                                       int B) {
    constexpr int F = 50;
    constexpr int C4 = 16;  // float4 columns per row (E=64)
    const int wid = threadIdx.x >> 6;           // wave in block (0..3)
    const int lane = threadIdx.x & 63;
    const int b = blockIdx.x * 4 + wid;         // one wave per batch
    if (b >= B) return;

    const int c4 = lane & 15;                   // float4 column 0..15
    const int fs = lane >> 4;                   // row phase 0..3

    const float4* xb = reinterpret_cast<const float4*>(x) + (size_t)b * F * C4;
    const float4* xp = xb + fs * C4 + c4;

    float4 s  = make_float4(0.f, 0.f, 0.f, 0.f);
    float4 ss = make_float4(0.f, 0.f, 0.f, 0.f);

    // rows f = fs + 4*k, k = 0..11  (covers f in [0,48))
#pragma unroll
    for (int k = 0; k < 12; ++k) {
        float4 v = xp[k * 4 * C4];
        s.x += v.x; s.y += v.y; s.z += v.z; s.w += v.w;
        ss.x = fmaf(v.x, v.x, ss.x);
        ss.y = fmaf(v.y, v.y, ss.y);
        ss.z = fmaf(v.z, v.z, ss.z);
        ss.w = fmaf(v.w, v.w, ss.w);
    }
    // tail rows 48, 49: phases 0 and 1 take one extra row each
    if (fs < 2) {
        float4 v = xb[(48 + fs) * C4 + c4];
        s.x += v.x; s.y += v.y; s.z += v.z; s.w += v.w;
        ss.x = fmaf(v.x, v.x, ss.x);
        ss.y = fmaf(v.y, v.y, ss.y);
        ss.z = fmaf(v.z, v.z, ss.z);
        ss.w = fmaf(v.w, v.w, ss.w);
    }

    // combine the 4 row-phases: xor 16 then xor 32 (width 64)
#pragma unroll
    for (int m = 16; m <= 32; m <<= 1) {
        s.x += __shfl_xor(s.x, m);  s.y += __shfl_xor(s.y, m);
        s.z += __shfl_xor(s.z, m);  s.w += __shfl_xor(s.w, m);
        ss.x += __shfl_xor(ss.x, m); ss.y += __shfl_xor(ss.y, m);
        ss.z += __shfl_xor(ss.z, m); ss.w += __shfl_xor(ss.w, m);
    }

    if (fs == 0) {
        float4 o;
        o.x = 0.5f * (s.x * s.x - ss.x);
        o.y = 0.5f * (s.y * s.y - ss.y);
        o.z = 0.5f * (s.z * s.z - ss.z);
        o.w = 0.5f * (s.w * s.w - ss.w);
        reinterpret_cast<float4*>(out)[(size_t)b * C4 + c4] = o;
    }
}

// Generic fallback for unexpected shapes (float2 per thread over full F).
__global__ __launch_bounds__(256) void afm_sum_generic(const float* __restrict__ x,
                                                       float* __restrict__ out,
                                                       int B, int E, int F) {
    const int ecols = E >> 1;
    const int total = B * ecols;
    int tid = blockIdx.x * blockDim.x + threadIdx.x;
    if (tid >= total) return;
    int b = tid / ecols;
    int c = tid - b * ecols;

    const float2* xp = reinterpret_cast<const float2*>(x) + (size_t)b * F * ecols + c;

    float2 s  = make_float2(0.f, 0.f);
    float2 ss = make_float2(0.f, 0.f);
#pragma unroll 10
    for (int f = 0; f < F; ++f) {
        float2 v = xp[(size_t)f * ecols];
        s.x += v.x;
        s.y += v.y;
        ss.x = fmaf(v.x, v.x, ss.x);
        ss.y = fmaf(v.y, v.y, ss.y);
    }

    float2 o;
    o.x = 0.5f * (s.x * s.x - ss.x);
    o.y = 0.5f * (s.y * s.y - ss.y);
    reinterpret_cast<float2*>(out)[tid] = o;
}

extern "C" void kernel_launch(void* const* d_in, const int* in_sizes, int n_in,
                              void* d_out, int out_size, void* d_ws, size_t ws_size,
                              hipStream_t stream) {
    const float* x = (const float*)d_in[0];  // [B, F, E] float32
    float* out = (float*)d_out;              // [B, E] float32

    // in_sizes[0]=B*F*E, in_sizes[1]=E*A, in_sizes[2]=A; out_size=B*E
    const int A = in_sizes[2];
    const int E = in_sizes[1] / A;
    const int B = out_size / E;
    const int F = in_sizes[0] / (B * E);

    if (F == 50 && E == 64) {
        const int block = 256;                 // 4 waves/block, 1 batch/wave
        const int grid = (B + 3) / 4;          // 512 blocks for B=2048
        afm_wave_kernel<<<grid, block, 0, stream>>>(x, out, B);
    } else {
        const int total = B * (E >> 1);
        const int block = 256;
        const int grid = (total + block - 1) / block;
        afm_sum_generic<<<grid, block, 0, stream>>>(x, out, B, E, F);
    }
}